// Round 11
// baseline (482.365 us; speedup 1.0000x reference)
//
#include <hip/hip_runtime.h>
#include <stdint.h>

// 3-layer binary net. L0: separable count tables + bit-pack. L1: i8 0/1 MFMA GEMM
// (matches = 1024 - popx - popm + 2*s01, thresholds folded). L2: popcount (tiny).
// ws: X1p 65536*32 u32 @0 (8MB) | cA | cB | M2p | c[1024] i32 | M01 1MB | X2p 8MB
#define WS_CA   8388608
#define WS_CB   8650752
#define WS_M2P  8912896
#define WS_C    8916992
#define WS_M01  8921088
#define WS_X2   9969664

typedef int v4i  __attribute__((ext_vector_type(4)));
typedef int v16i __attribute__((ext_vector_type(16)));

// 16 bits -> 16 bytes (0/1), byte e = bit e. nibble spread: (n*0x204081)&0x01010101
__device__ __forceinline__ v4i expand16(unsigned h) {
  v4i a;
  a.x = (int)(__umul24(h & 15u,         0x00204081u) & 0x01010101u);
  a.y = (int)(__umul24((h >> 4) & 15u,  0x00204081u) & 0x01010101u);
  a.z = (int)(__umul24((h >> 8) & 15u,  0x00204081u) & 0x01010101u);
  a.w = (int)(__umul24((h >> 12) & 15u, 0x00204081u) & 0x01010101u);
  return a;
}

// ---- mask upload-format sniffing (bool arrays may arrive as u8, i32, or f32) ----
__device__ inline int detect_mode(const unsigned char* p) {
  unsigned nonalign = 0;
  for (int i = 0; i < 64; i++)
    if (i & 3) nonalign |= p[i];
  if (nonalign == 0) return 1;                 // int32 0/1
  bool f32ok = true;
  for (int e = 0; e < 16; e++) {
    const unsigned char* q = p + 4 * e;
    bool one  = (q[0] == 0 && q[1] == 0 && q[2] == 0x80 && q[3] == 0x3F);
    bool zero = (q[0] == 0 && q[1] == 0 && q[2] == 0 && q[3] == 0);
    if (!(one || zero)) { f32ok = false; break; }
  }
  return f32ok ? 2 : 0;
}

__device__ inline int maskbit(const unsigned char* p, int idx, int mode) {
  if (mode == 1) return ((const int*)p)[idx] & 1;
  if (mode == 2) return ((const float*)p)[idx] != 0.0f;
  return p[idx] & 1;
}

__global__ __launch_bounds__(256) void prep_kernel(
    const unsigned char* __restrict__ mask0, const int* __restrict__ thr0,
    const unsigned char* __restrict__ mask1, const unsigned char* __restrict__ mask2,
    const int* __restrict__ thr1,
    signed char* __restrict__ cA, unsigned char* __restrict__ cB,
    unsigned* __restrict__ M01w, unsigned* __restrict__ M2p,
    int* __restrict__ carr) {
  __shared__ int smode;
  if (threadIdx.x == 0) smode = detect_mode(mask1);
  __syncthreads();
  int mode = smode;
  int gid = blockIdx.x * 256 + threadIdx.x;
  if (gid < 524288) {              // cA / cB tables for L0
    int which = gid >> 18;
    int idx = gid & 262143;
    int hw = idx >> 10;
    int o  = idx & 1023;
    int base = which ? 8 : 0;
    int cnt = 0;
#pragma unroll
    for (int i = 0; i < 8; i++) {
      int xb = (hw >> (7 - i)) & 1;                     // MSB-first bits
      int mb = maskbit(mask0, (base + i) * 1024 + o, mode);
      cnt += (xb == mb);
    }
    if (which) cB[idx] = (unsigned char)cnt;
    else       cA[idx] = (signed char)(cnt - thr0[o]);
    return;
  }
  int g1 = gid - 524288;
  if (g1 < 262144) {               // M01 expand: u32 = 4 bytes = feats 4kk..4kk+3 of out o
    int o = g1 & 1023;
    int kk = g1 >> 10;             // 0..255
    unsigned u = 0;
#pragma unroll
    for (int j = 0; j < 4; j++)
      u |= (unsigned)maskbit(mask1, (4 * kk + j) * 1024 + o, mode) << (8 * j);
    M01w[o * 256 + kk] = u;
    return;
  }
  int g2 = g1 - 262144;
  if (g2 < 768) {                  // pack mask2: M2p[o][kw], LSB-first
    int kw = g2 / 24, o = g2 % 24;
    unsigned wv = 0;
    for (int b = 0; b < 32; b++)
      wv |= (unsigned)maskbit(mask2, (kw * 32 + b) * 24 + o, mode) << b;
    M2p[o * 32 + kw] = wv;
    return;
  }
  int g3 = g2 - 768;
  if (g3 < 1024) {                 // popm + folded threshold c[o]
    int o = g3;
    int pm = 0;
#pragma unroll 8
    for (int k = 0; k < 1024; k++)
      pm += maskbit(mask1, k * 1024 + o, mode);
    carr[o] = thr1[o] + pm - 1024;
  }
}

// Layer-0 evaluate + bit-pack (1 px per block).
__global__ __launch_bounds__(256) void pack_x1(
    const signed char* __restrict__ cA, const unsigned char* __restrict__ cB,
    unsigned* __restrict__ X1p) {
  int t = threadIdx.x;
  int lane = t & 63;
  int q = t >> 6;
  int n = blockIdx.x;
  int h = n >> 8, w = n & 255;
  const signed char*   ca = cA + h * 1024;
  const unsigned char* cb = cB + w * 1024;
#pragma unroll
  for (int j = 0; j < 4; j++) {
    int o = q * 256 + j * 64 + lane;
    bool bit = ((int)ca[o] + (int)cb[o]) > 0;
    unsigned long long bal = __ballot(bit);
    if (lane == 0) {
      uint2 v; v.x = (unsigned)bal; v.y = (unsigned)(bal >> 32);
      *reinterpret_cast<uint2*>(&X1p[n * 32 + q * 8 + 2 * j]) = v;
    }
  }
}

// Main: L1 as i8 MFMA GEMM. Block = 128 px x 512 outs (grid 1024, 4 blocks/CU).
// Wave w owns 128 outs (4 sub-chunks of 32); per sub-chunk: acc[4 rt] of 32x32,
// K = 1024 in 32 steps of 32. A (pixels) from LDS-transposed packed bits,
// expanded in-register; B (M01 i8) streamed from L2 with 1-deep prefetch.
// k-permutation safety: A elem e and B elem e both carry feature 32ks+16g+e,
// so any shared HW (g,e)->k map gives the correct dot product.
__global__ __launch_bounds__(256) void main_kernel(
    const uint4* __restrict__ X1p4, const unsigned char* __restrict__ M01,
    const int* __restrict__ carr, unsigned* __restrict__ X2p) {
  __shared__ unsigned short lxT[64 * 128];   // [halfword hw][row] 16 KB
  __shared__ unsigned ppop[256];
  __shared__ unsigned popx[128];
  int t = threadIdx.x;
  int pb = blockIdx.x >> 1;
  int half = blockIdx.x & 1;
  int n0 = pb << 7;

  // stage + transpose + row-popcounts
  {
    int r = t >> 1;
    int u0 = (t & 1) * 4;          // first uint4 index (of 8) in the row
    unsigned pc = 0;
#pragma unroll
    for (int q = 0; q < 4; q++) {
      int u = u0 + q;
      uint4 v = X1p4[(n0 + r) * 8 + u];
      pc += __popc(v.x) + __popc(v.y) + __popc(v.z) + __popc(v.w);
      lxT[(8 * u + 0) * 128 + r] = (unsigned short)(v.x & 0xFFFFu);
      lxT[(8 * u + 1) * 128 + r] = (unsigned short)(v.x >> 16);
      lxT[(8 * u + 2) * 128 + r] = (unsigned short)(v.y & 0xFFFFu);
      lxT[(8 * u + 3) * 128 + r] = (unsigned short)(v.y >> 16);
      lxT[(8 * u + 4) * 128 + r] = (unsigned short)(v.z & 0xFFFFu);
      lxT[(8 * u + 5) * 128 + r] = (unsigned short)(v.z >> 16);
      lxT[(8 * u + 6) * 128 + r] = (unsigned short)(v.w & 0xFFFFu);
      lxT[(8 * u + 7) * 128 + r] = (unsigned short)(v.w >> 16);
    }
    ppop[t] = pc;
  }
  __syncthreads();
  if (t < 128) popx[t] = ppop[2 * t] + ppop[2 * t + 1];
  __syncthreads();

  int lane = t & 63;
  int w = t >> 6;                  // wave id: owns outs [half*512+w*128, +128)
  int g = lane >> 5;               // k-group within fragment
  int col = lane & 31;             // output column within 32-chunk / A row offset

#pragma unroll 1
  for (int s = 0; s < 4; s++) {
    int obase = half * 512 + w * 128 + s * 32;
    const unsigned char* bp = M01 + (unsigned)(obase + col) * 1024 + g * 16;

    v16i a0 = {0,0,0,0,0,0,0,0,0,0,0,0,0,0,0,0};
    v16i a1 = a0, a2 = a0, a3 = a0;

    v4i bnext = *reinterpret_cast<const v4i*>(bp);
#pragma unroll 1
    for (int ks = 0; ks < 32; ks++) {
      v4i bv = bnext;
      if (ks < 31) bnext = *reinterpret_cast<const v4i*>(bp + 32 * (ks + 1));
      int hw = 2 * ks + g;
      unsigned h0 = lxT[hw * 128 +  0 + col];
      unsigned h1 = lxT[hw * 128 + 32 + col];
      unsigned h2 = lxT[hw * 128 + 64 + col];
      unsigned h3 = lxT[hw * 128 + 96 + col];
      a0 = __builtin_amdgcn_mfma_i32_32x32x32_i8(expand16(h0), bv, a0, 0, 0, 0);
      a1 = __builtin_amdgcn_mfma_i32_32x32x32_i8(expand16(h1), bv, a1, 0, 0, 0);
      a2 = __builtin_amdgcn_mfma_i32_32x32x32_i8(expand16(h2), bv, a2, 0, 0, 0);
      a3 = __builtin_amdgcn_mfma_i32_32x32x32_i8(expand16(h3), bv, a3, 0, 0, 0);
    }

    // threshold + ballot-pack -> X2p. C/D: col=lane&31, row=(reg&3)+8*(reg>>2)+4*g.
    int cv = carr[obase + col];
    int kw = obase >> 5;
#pragma unroll
    for (int rt = 0; rt < 4; rt++) {
      v16i av = (rt == 0) ? a0 : (rt == 1) ? a1 : (rt == 2) ? a2 : a3;
#pragma unroll
      for (int reg = 0; reg < 16; reg++) {
        int px_lo = 32 * rt + (reg & 3) + 8 * (reg >> 2);
        int px    = px_lo + 4 * g;
        bool bit = (2 * av[reg] > cv + (int)popx[px]);
        unsigned long long bal = __ballot(bit);
        if (lane == 0) {
          X2p[(unsigned)(n0 + px_lo) * 32 + kw]     = (unsigned)bal;
          X2p[(unsigned)(n0 + px_lo + 4) * 32 + kw] = (unsigned)(bal >> 32);
        }
      }
    }
  }
}

// Layer 2 + epilogue: 256 px/block, one px/thread.
__global__ __launch_bounds__(256) void l2_kernel(
    const uint4* __restrict__ X2p4, const unsigned* __restrict__ M2p,
    const int* __restrict__ thr2, const float* __restrict__ image,
    float* __restrict__ out) {
  __shared__ unsigned lm2[768];
  int t = threadIdx.x;
  for (int r = t; r < 768; r += 256) lm2[r] = M2p[r];
  __syncthreads();
  int n = blockIdx.x * 256 + t;
  uint4 xw[8];
#pragma unroll
  for (int q = 0; q < 8; q++) xw[q] = X2p4[(unsigned)n * 8 + q];
#pragma unroll
  for (int c = 0; c < 3; c++) {
    int val = 0;
#pragma unroll
    for (int b = 0; b < 8; b++) {
      int o = c * 8 + b;
      const unsigned* m = &lm2[o * 32];
      unsigned acc2 = 0;
#pragma unroll
      for (int q = 0; q < 8; q++) {
        acc2 += __popc(xw[q].x ^ m[q * 4 + 0]);
        acc2 += __popc(xw[q].y ^ m[q * 4 + 1]);
        acc2 += __popc(xw[q].z ^ m[q * 4 + 2]);
        acc2 += __popc(xw[q].w ^ m[q * 4 + 3]);
      }
      int bit = ((int)(1024u - acc2)) > thr2[o];
      val |= bit << (7 - b);                            // MSB-first
    }
    out[c * 65536 + n] = (float)val;
    out[196608 + c * 65536 + n] = (float)val - image[c * 65536 + n];
  }
}

extern "C" void kernel_launch(void* const* d_in, const int* in_sizes, int n_in,
                              void* d_out, int out_size, void* d_ws, size_t ws_size,
                              hipStream_t stream) {
  const float*         image = (const float*)d_in[0];
  const unsigned char* mask0 = (const unsigned char*)d_in[1];
  const int*           thr0  = (const int*)d_in[2];
  const unsigned char* mask1 = (const unsigned char*)d_in[3];
  const int*           thr1  = (const int*)d_in[4];
  const unsigned char* mask2 = (const unsigned char*)d_in[5];
  const int*           thr2  = (const int*)d_in[6];
  char* ws = (char*)d_ws;
  unsigned*      X1p  = (unsigned*)(ws);
  signed char*   cA   = (signed char*)(ws + WS_CA);
  unsigned char* cB   = (unsigned char*)(ws + WS_CB);
  unsigned*      M2p  = (unsigned*)(ws + WS_M2P);
  int*           carr = (int*)(ws + WS_C);
  unsigned*      M01w = (unsigned*)(ws + WS_M01);
  unsigned*      X2p  = (unsigned*)(ws + WS_X2);
  float* out = (float*)d_out;

  hipLaunchKernelGGL(prep_kernel, dim3(3079), dim3(256), 0, stream,
                     mask0, thr0, mask1, mask2, thr1, cA, cB, M01w, M2p, carr);
  hipLaunchKernelGGL(pack_x1, dim3(65536), dim3(256), 0, stream, cA, cB, X1p);
  hipLaunchKernelGGL(main_kernel, dim3(1024), dim3(256), 0, stream,
                     (const uint4*)X1p, (const unsigned char*)M01w, carr, X2p);
  hipLaunchKernelGGL(l2_kernel, dim3(256), dim3(256), 0, stream,
                     (const uint4*)X2p, M2p, thr2, image, out);
}

// Round 12
// 192.640 us; speedup vs baseline: 2.5040x; 2.5040x over previous
//
#include <hip/hip_runtime.h>
#include <stdint.h>

// 3-layer binary net. L0: separable count tables + bit-pack. L1: i8 0/1 MFMA GEMM
// (matches = 1024 - popx - popm + 2*s01, thresholds folded). L2: popcount (tiny).
// ws: X1p 65536*32 u32 @0 (8MB) | cA | cB | M2p | c[1024] i32 | M01 1MB | X2p 8MB
#define WS_CA   8388608
#define WS_CB   8650752
#define WS_M2P  8912896
#define WS_C    8916992
#define WS_M01  8921088
#define WS_X2   9969664

typedef int v4i  __attribute__((ext_vector_type(4)));
typedef int v16i __attribute__((ext_vector_type(16)));

// 16 bits -> 16 bytes (0/1), byte e = bit e. nibble spread: (n*0x204081)&0x01010101
__device__ __forceinline__ v4i expand16(unsigned h) {
  v4i a;
  a.x = (int)(__umul24(h & 15u,         0x00204081u) & 0x01010101u);
  a.y = (int)(__umul24((h >> 4) & 15u,  0x00204081u) & 0x01010101u);
  a.z = (int)(__umul24((h >> 8) & 15u,  0x00204081u) & 0x01010101u);
  a.w = (int)(__umul24((h >> 12) & 15u, 0x00204081u) & 0x01010101u);
  return a;
}

// ---- mask upload-format sniffing (bool arrays may arrive as u8, i32, or f32) ----
__device__ inline int detect_mode(const unsigned char* p) {
  unsigned nonalign = 0;
  for (int i = 0; i < 64; i++)
    if (i & 3) nonalign |= p[i];
  if (nonalign == 0) return 1;                 // int32 0/1
  bool f32ok = true;
  for (int e = 0; e < 16; e++) {
    const unsigned char* q = p + 4 * e;
    bool one  = (q[0] == 0 && q[1] == 0 && q[2] == 0x80 && q[3] == 0x3F);
    bool zero = (q[0] == 0 && q[1] == 0 && q[2] == 0 && q[3] == 0);
    if (!(one || zero)) { f32ok = false; break; }
  }
  return f32ok ? 2 : 0;
}

__device__ inline int maskbit(const unsigned char* p, int idx, int mode) {
  if (mode == 1) return ((const int*)p)[idx] & 1;
  if (mode == 2) return ((const float*)p)[idx] != 0.0f;
  return p[idx] & 1;
}

__global__ __launch_bounds__(256) void prep_kernel(
    const unsigned char* __restrict__ mask0, const int* __restrict__ thr0,
    const unsigned char* __restrict__ mask1, const unsigned char* __restrict__ mask2,
    signed char* __restrict__ cA, unsigned char* __restrict__ cB,
    unsigned* __restrict__ M01w, unsigned* __restrict__ M2p) {
  __shared__ int smode;
  if (threadIdx.x == 0) smode = detect_mode(mask1);
  __syncthreads();
  int mode = smode;
  int gid = blockIdx.x * 256 + threadIdx.x;
  if (gid < 524288) {              // cA / cB tables for L0
    int which = gid >> 18;
    int idx = gid & 262143;
    int hw = idx >> 10;
    int o  = idx & 1023;
    int base = which ? 8 : 0;
    int cnt = 0;
#pragma unroll
    for (int i = 0; i < 8; i++) {
      int xb = (hw >> (7 - i)) & 1;                     // MSB-first bits
      int mb = maskbit(mask0, (base + i) * 1024 + o, mode);
      cnt += (xb == mb);
    }
    if (which) cB[idx] = (unsigned char)cnt;
    else       cA[idx] = (signed char)(cnt - thr0[o]);
    return;
  }
  int g1 = gid - 524288;
  if (g1 < 262144) {               // M01 expand: u32 = 4 bytes = feats 4kk..4kk+3 of out o
    int o = g1 & 1023;
    int kk = g1 >> 10;             // 0..255
    unsigned u = 0;
#pragma unroll
    for (int j = 0; j < 4; j++)
      u |= (unsigned)maskbit(mask1, (4 * kk + j) * 1024 + o, mode) << (8 * j);
    M01w[o * 256 + kk] = u;
    return;
  }
  int g2 = g1 - 262144;
  if (g2 < 768) {                  // pack mask2: M2p[o][kw], LSB-first
    int kw = g2 / 24, o = g2 % 24;
    unsigned wv = 0;
    for (int b = 0; b < 32; b++)
      wv |= (unsigned)maskbit(mask2, (kw * 32 + b) * 24 + o, mode) << b;
    M2p[o * 32 + kw] = wv;
  }
}

// popm reduction over expanded M01w (bytes 0/1 -> only bits 0/8/16/24 set, so
// popc(u32) = byte sum). One block per output o; coalesced 1KB read + reduce.
// R11 lesson: the serial per-thread popm loop over raw mask1 was 317us.
__global__ __launch_bounds__(256) void popm_kernel(
    const unsigned* __restrict__ M01w, const int* __restrict__ thr1,
    int* __restrict__ carr) {
  __shared__ int part[4];
  int t = threadIdx.x;
  int o = blockIdx.x;
  int v = __popc(M01w[o * 256 + t]);
#pragma unroll
  for (int d = 32; d >= 1; d >>= 1) v += __shfl_down(v, d);
  if ((t & 63) == 0) part[t >> 6] = v;
  __syncthreads();
  if (t == 0)
    carr[o] = thr1[o] + (part[0] + part[1] + part[2] + part[3]) - 1024;
}

// Layer-0 evaluate + bit-pack (1 px per block).
__global__ __launch_bounds__(256) void pack_x1(
    const signed char* __restrict__ cA, const unsigned char* __restrict__ cB,
    unsigned* __restrict__ X1p) {
  int t = threadIdx.x;
  int lane = t & 63;
  int q = t >> 6;
  int n = blockIdx.x;
  int h = n >> 8, w = n & 255;
  const signed char*   ca = cA + h * 1024;
  const unsigned char* cb = cB + w * 1024;
#pragma unroll
  for (int j = 0; j < 4; j++) {
    int o = q * 256 + j * 64 + lane;
    bool bit = ((int)ca[o] + (int)cb[o]) > 0;
    unsigned long long bal = __ballot(bit);
    if (lane == 0) {
      uint2 v; v.x = (unsigned)bal; v.y = (unsigned)(bal >> 32);
      *reinterpret_cast<uint2*>(&X1p[n * 32 + q * 8 + 2 * j]) = v;
    }
  }
}

// Main: L1 as i8 MFMA GEMM. Block = 128 px x 512 outs (grid 1024, 4 blocks/CU).
// Wave w owns 128 outs (4 sub-chunks of 32); per sub-chunk: acc[4 rt] of 32x32,
// K = 1024 in 32 steps of 32. A (pixels) from LDS-transposed packed bits,
// expanded in-register; B (M01 i8) streamed from L2 with 1-deep prefetch.
// k-permutation safety: A elem e and B elem e both carry feature 32ks+16g+e,
// so any shared HW (g,e)->k map gives the correct dot product.
__global__ __launch_bounds__(256) void main_kernel(
    const uint4* __restrict__ X1p4, const unsigned char* __restrict__ M01,
    const int* __restrict__ carr, unsigned* __restrict__ X2p) {
  __shared__ unsigned short lxT[64 * 128];   // [halfword hw][row] 16 KB
  __shared__ unsigned ppop[256];
  __shared__ unsigned popx[128];
  int t = threadIdx.x;
  int pb = blockIdx.x >> 1;
  int half = blockIdx.x & 1;
  int n0 = pb << 7;

  // stage + transpose + row-popcounts
  {
    int r = t >> 1;
    int u0 = (t & 1) * 4;          // first uint4 index (of 8) in the row
    unsigned pc = 0;
#pragma unroll
    for (int q = 0; q < 4; q++) {
      int u = u0 + q;
      uint4 v = X1p4[(n0 + r) * 8 + u];
      pc += __popc(v.x) + __popc(v.y) + __popc(v.z) + __popc(v.w);
      lxT[(8 * u + 0) * 128 + r] = (unsigned short)(v.x & 0xFFFFu);
      lxT[(8 * u + 1) * 128 + r] = (unsigned short)(v.x >> 16);
      lxT[(8 * u + 2) * 128 + r] = (unsigned short)(v.y & 0xFFFFu);
      lxT[(8 * u + 3) * 128 + r] = (unsigned short)(v.y >> 16);
      lxT[(8 * u + 4) * 128 + r] = (unsigned short)(v.z & 0xFFFFu);
      lxT[(8 * u + 5) * 128 + r] = (unsigned short)(v.z >> 16);
      lxT[(8 * u + 6) * 128 + r] = (unsigned short)(v.w & 0xFFFFu);
      lxT[(8 * u + 7) * 128 + r] = (unsigned short)(v.w >> 16);
    }
    ppop[t] = pc;
  }
  __syncthreads();
  if (t < 128) popx[t] = ppop[2 * t] + ppop[2 * t + 1];
  __syncthreads();

  int lane = t & 63;
  int w = t >> 6;                  // wave id: owns outs [half*512+w*128, +128)
  int g = lane >> 5;               // k-group within fragment
  int col = lane & 31;             // output column within 32-chunk / A row offset

#pragma unroll 1
  for (int s = 0; s < 4; s++) {
    int obase = half * 512 + w * 128 + s * 32;
    const unsigned char* bp = M01 + (unsigned)(obase + col) * 1024 + g * 16;

    v16i a0 = {0,0,0,0,0,0,0,0,0,0,0,0,0,0,0,0};
    v16i a1 = a0, a2 = a0, a3 = a0;

    v4i bnext = *reinterpret_cast<const v4i*>(bp);
#pragma unroll 1
    for (int ks = 0; ks < 32; ks++) {
      v4i bv = bnext;
      if (ks < 31) bnext = *reinterpret_cast<const v4i*>(bp + 32 * (ks + 1));
      int hw = 2 * ks + g;
      unsigned h0 = lxT[hw * 128 +  0 + col];
      unsigned h1 = lxT[hw * 128 + 32 + col];
      unsigned h2 = lxT[hw * 128 + 64 + col];
      unsigned h3 = lxT[hw * 128 + 96 + col];
      a0 = __builtin_amdgcn_mfma_i32_32x32x32_i8(expand16(h0), bv, a0, 0, 0, 0);
      a1 = __builtin_amdgcn_mfma_i32_32x32x32_i8(expand16(h1), bv, a1, 0, 0, 0);
      a2 = __builtin_amdgcn_mfma_i32_32x32x32_i8(expand16(h2), bv, a2, 0, 0, 0);
      a3 = __builtin_amdgcn_mfma_i32_32x32x32_i8(expand16(h3), bv, a3, 0, 0, 0);
    }

    // threshold + ballot-pack -> X2p. C/D: col=lane&31, row=(reg&3)+8*(reg>>2)+4*g.
    int cv = carr[obase + col];
    int kw = obase >> 5;
#pragma unroll
    for (int rt = 0; rt < 4; rt++) {
      v16i av = (rt == 0) ? a0 : (rt == 1) ? a1 : (rt == 2) ? a2 : a3;
#pragma unroll
      for (int reg = 0; reg < 16; reg++) {
        int px_lo = 32 * rt + (reg & 3) + 8 * (reg >> 2);
        int px    = px_lo + 4 * g;
        bool bit = (2 * av[reg] > cv + (int)popx[px]);
        unsigned long long bal = __ballot(bit);
        if (lane == 0) {
          X2p[(unsigned)(n0 + px_lo) * 32 + kw]     = (unsigned)bal;
          X2p[(unsigned)(n0 + px_lo + 4) * 32 + kw] = (unsigned)(bal >> 32);
        }
      }
    }
  }
}

// Layer 2 + epilogue: 256 px/block, one px/thread.
__global__ __launch_bounds__(256) void l2_kernel(
    const uint4* __restrict__ X2p4, const unsigned* __restrict__ M2p,
    const int* __restrict__ thr2, const float* __restrict__ image,
    float* __restrict__ out) {
  __shared__ unsigned lm2[768];
  int t = threadIdx.x;
  for (int r = t; r < 768; r += 256) lm2[r] = M2p[r];
  __syncthreads();
  int n = blockIdx.x * 256 + t;
  uint4 xw[8];
#pragma unroll
  for (int q = 0; q < 8; q++) xw[q] = X2p4[(unsigned)n * 8 + q];
#pragma unroll
  for (int c = 0; c < 3; c++) {
    int val = 0;
#pragma unroll
    for (int b = 0; b < 8; b++) {
      int o = c * 8 + b;
      const unsigned* m = &lm2[o * 32];
      unsigned acc2 = 0;
#pragma unroll
      for (int q = 0; q < 8; q++) {
        acc2 += __popc(xw[q].x ^ m[q * 4 + 0]);
        acc2 += __popc(xw[q].y ^ m[q * 4 + 1]);
        acc2 += __popc(xw[q].z ^ m[q * 4 + 2]);
        acc2 += __popc(xw[q].w ^ m[q * 4 + 3]);
      }
      int bit = ((int)(1024u - acc2)) > thr2[o];
      val |= bit << (7 - b);                            // MSB-first
    }
    out[c * 65536 + n] = (float)val;
    out[196608 + c * 65536 + n] = (float)val - image[c * 65536 + n];
  }
}

extern "C" void kernel_launch(void* const* d_in, const int* in_sizes, int n_in,
                              void* d_out, int out_size, void* d_ws, size_t ws_size,
                              hipStream_t stream) {
  const float*         image = (const float*)d_in[0];
  const unsigned char* mask0 = (const unsigned char*)d_in[1];
  const int*           thr0  = (const int*)d_in[2];
  const unsigned char* mask1 = (const unsigned char*)d_in[3];
  const int*           thr1  = (const int*)d_in[4];
  const unsigned char* mask2 = (const unsigned char*)d_in[5];
  const int*           thr2  = (const int*)d_in[6];
  char* ws = (char*)d_ws;
  unsigned*      X1p  = (unsigned*)(ws);
  signed char*   cA   = (signed char*)(ws + WS_CA);
  unsigned char* cB   = (unsigned char*)(ws + WS_CB);
  unsigned*      M2p  = (unsigned*)(ws + WS_M2P);
  int*           carr = (int*)(ws + WS_C);
  unsigned*      M01w = (unsigned*)(ws + WS_M01);
  unsigned*      X2p  = (unsigned*)(ws + WS_X2);
  float* out = (float*)d_out;

  hipLaunchKernelGGL(prep_kernel, dim3(3075), dim3(256), 0, stream,
                     mask0, thr0, mask1, mask2, cA, cB, M01w, M2p);
  hipLaunchKernelGGL(popm_kernel, dim3(1024), dim3(256), 0, stream,
                     M01w, thr1, carr);
  hipLaunchKernelGGL(pack_x1, dim3(65536), dim3(256), 0, stream, cA, cB, X1p);
  hipLaunchKernelGGL(main_kernel, dim3(1024), dim3(256), 0, stream,
                     (const uint4*)X1p, (const unsigned char*)M01w, carr, X2p);
  hipLaunchKernelGGL(l2_kernel, dim3(256), dim3(256), 0, stream,
                     (const uint4*)X2p, M2p, thr2, image, out);
}

// Round 14
// 184.276 us; speedup vs baseline: 2.6176x; 1.0454x over previous
//
#include <hip/hip_runtime.h>
#include <stdint.h>

// 3-layer binary net. L0: separable tables + bit-pack (transposed). L1: i8 MFMA
// GEMM, A(X) pre-expanded to LDS once/block, B(M01) in fragment-order ws layout.
// L2 + epilogue fused into main. matches = 1024 - popx - popm + 2*s01, folded.
// ws: X1pT 32*65536 u32 @0 (8MB) | popxA u16 128KB | cA 256K | cB 256K |
//     M2p 3KB | carr 4KB | Bf 1MB
#define WS_POPX 8388608
#define WS_CA   8519680
#define WS_CB   8781824
#define WS_M2P  9043968
#define WS_CARR 9047040
#define WS_BF   9051136

typedef int v4i  __attribute__((ext_vector_type(4)));
typedef int v16i __attribute__((ext_vector_type(16)));

// 16 bits -> 16 bytes (0/1), byte e = bit e (LSB-first)
__device__ __forceinline__ v4i expand16(unsigned h) {
  v4i a;
  a.x = (int)(__umul24(h & 15u,         0x00204081u) & 0x01010101u);
  a.y = (int)(__umul24((h >> 4) & 15u,  0x00204081u) & 0x01010101u);
  a.z = (int)(__umul24((h >> 8) & 15u,  0x00204081u) & 0x01010101u);
  a.w = (int)(__umul24((h >> 12) & 15u, 0x00204081u) & 0x01010101u);
  return a;
}

// ---- mask upload-format sniffing (bool arrays may arrive as u8, i32, or f32) ----
__device__ inline int detect_mode(const unsigned char* p) {
  unsigned nonalign = 0;
  for (int i = 0; i < 64; i++)
    if (i & 3) nonalign |= p[i];
  if (nonalign == 0) return 1;                 // int32 0/1
  bool f32ok = true;
  for (int e = 0; e < 16; e++) {
    const unsigned char* q = p + 4 * e;
    bool one  = (q[0] == 0 && q[1] == 0 && q[2] == 0x80 && q[3] == 0x3F);
    bool zero = (q[0] == 0 && q[1] == 0 && q[2] == 0 && q[3] == 0);
    if (!(one || zero)) { f32ok = false; break; }
  }
  return f32ok ? 2 : 0;
}

__device__ inline int maskbit(const unsigned char* p, int idx, int mode) {
  if (mode == 1) return ((const int*)p)[idx] & 1;
  if (mode == 2) return ((const float*)p)[idx] != 0.0f;
  return p[idx] & 1;
}

__global__ __launch_bounds__(256) void prep_kernel(
    const unsigned char* __restrict__ mask0, const int* __restrict__ thr0,
    const unsigned char* __restrict__ mask1, const unsigned char* __restrict__ mask2,
    signed char* __restrict__ cA, unsigned char* __restrict__ cB,
    unsigned char* __restrict__ Bf, unsigned* __restrict__ M2p) {
  __shared__ int smode;
  if (threadIdx.x == 0) smode = detect_mode(mask1);
  __syncthreads();
  int mode = smode;
  int gid = blockIdx.x * 256 + threadIdx.x;
  if (gid < 524288) {              // cA / cB tables for L0
    int which = gid >> 18;
    int idx = gid & 262143;
    int hw = idx >> 10;
    int o  = idx & 1023;
    int base = which ? 8 : 0;
    int cnt = 0;
#pragma unroll
    for (int i = 0; i < 8; i++) {
      int xb = (hw >> (7 - i)) & 1;                     // MSB-first bits
      int mb = maskbit(mask0, (base + i) * 1024 + o, mode);
      cnt += (xb == mb);
    }
    if (which) cB[idx] = (unsigned char)cnt;
    else       cA[idx] = (signed char)(cnt - thr0[o]);
    return;
  }
  int g1 = gid - 524288;
  if (g1 < 262144) {               // M01 -> Bf fragment layout (i8, MFMA B order)
    int o  = g1 & 1023;
    int kk = g1 >> 10;             // u32 chunk: feats 4kk..4kk+3
    unsigned u = 0;
#pragma unroll
    for (int j = 0; j < 4; j++)
      u |= (unsigned)maskbit(mask1, (4 * kk + j) * 1024 + o, mode) << (8 * j);
    // feat f=4kk: ks=kk>>3, g=(kk>>2)&1, e0=4*(kk&3); frag = [oc32][ks][g][col]
    unsigned off = ((unsigned)(o >> 5) << 15) + ((unsigned)(kk >> 3) << 10) +
                   ((unsigned)((kk >> 2) & 1) << 9) + ((unsigned)(o & 31) << 4) +
                   ((unsigned)(kk & 3) << 2);
    *reinterpret_cast<unsigned*>(Bf + off) = u;
    return;
  }
  int g2 = g1 - 262144;
  if (g2 < 768) {                  // pack mask2: M2p[o][kw], LSB-first
    int kw = g2 / 24, o = g2 % 24;
    unsigned wv = 0;
    for (int b = 0; b < 32; b++)
      wv |= (unsigned)maskbit(mask2, (kw * 32 + b) * 24 + o, mode) << b;
    M2p[o * 32 + kw] = wv;
  }
}

// popm: column-sum of Bf (bytes 0/1 -> popc per u32 = byte sum). 1 wave per o.
__global__ __launch_bounds__(64) void popm_kernel(
    const unsigned char* __restrict__ Bf, const int* __restrict__ thr1,
    int* __restrict__ carr) {
  int o = blockIdx.x;
  int t = threadIdx.x;               // t = ks*2+g
  const uint4* p = reinterpret_cast<const uint4*>(
      Bf + ((unsigned)(o >> 5) << 15) + ((unsigned)(t >> 1) << 10) +
      ((unsigned)(t & 1) << 9) + ((unsigned)(o & 31) << 4));
  uint4 v = *p;
  int s = __popc(v.x) + __popc(v.y) + __popc(v.z) + __popc(v.w);
#pragma unroll
  for (int d = 32; d >= 1; d >>= 1) s += __shfl_down(s, d);
  if (t == 0) carr[o] = thr1[o] + s - 1024;
}

// Layer-0 evaluate + bit-pack, TRANSPOSED output X1pT[w][n] + per-pixel popx.
__global__ __launch_bounds__(256) void pack_x1(
    const signed char* __restrict__ cA, const unsigned char* __restrict__ cB,
    unsigned* __restrict__ X1pT, unsigned short* __restrict__ popxA) {
  __shared__ unsigned pp[4];
  int t = threadIdx.x;
  int lane = t & 63;
  int q = t >> 6;
  int n = blockIdx.x;
  int h = n >> 8, w = n & 255;
  const signed char*   ca = cA + h * 1024;
  const unsigned char* cb = cB + w * 1024;
  unsigned pc = 0;
#pragma unroll
  for (int j = 0; j < 4; j++) {
    int o = q * 256 + j * 64 + lane;
    bool bit = ((int)ca[o] + (int)cb[o]) > 0;          // cA+cB > thr0
    unsigned long long bal = __ballot(bit);
    if (lane == 0) {
      int wd = q * 8 + 2 * j;
      X1pT[wd * 65536 + n]       = (unsigned)bal;
      X1pT[(wd + 1) * 65536 + n] = (unsigned)(bal >> 32);
      pc += __popcll(bal);
    }
  }
  if (lane == 0) pp[q] = pc;
  __syncthreads();
  if (t == 0) popxA[n] = (unsigned short)(pp[0] + pp[1] + pp[2] + pp[3]);
}

// Main: block = 64 px x 1024 outs, 512 threads (8 waves), grid 1024.
// A (X, i8) expanded ONCE into 64KB LDS; B streamed coalesced from Bf (L2-hot).
// Wave owns 4 oc32 chunks as 2 sblk x 2 s; acc[2s][2rt] = 64 VGPR; 1-deep
// prefetch on A and B. Fused threshold -> xbits(LDS) -> L2 popcount -> output.
__global__ __launch_bounds__(512) void main_kernel(
    const unsigned* __restrict__ X1pT, const unsigned char* __restrict__ Bf,
    const int* __restrict__ carr, const unsigned short* __restrict__ popxA,
    const unsigned* __restrict__ M2p, const int* __restrict__ thr2,
    const float* __restrict__ image, float* __restrict__ out) {
  __shared__ v4i Ae4[4096];          // 64 KB  [ks 0..31][g 0..1][row 0..63] x 16B
  __shared__ unsigned xbits[2048];   //  8 KB  [px 0..63][oc 0..31]
  __shared__ unsigned lm2[768];      //  3 KB
  __shared__ int spopx[64];
  int t = threadIdx.x;
  int n0 = blockIdx.x << 6;

  for (int r = t; r < 768; r += 512) lm2[r] = M2p[r];
  if (t < 64) spopx[t] = (int)popxA[n0 + t];

  // cooperative expand: X1pT (coalesced uint2 per thread) -> i8 LDS
#pragma unroll
  for (int wl = 0; wl < 2; wl++) {
    int w = wl * 16 + (t >> 5);      // halfword-pair index 0..31 -> (ks,g)
    int rp = (t & 31) * 2;
    uint2 v = *reinterpret_cast<const uint2*>(&X1pT[w * 65536 + n0 + rp]);
    Ae4[w * 128 + rp]          = expand16(v.x & 0xFFFFu);
    Ae4[w * 128 + 64 + rp]     = expand16(v.x >> 16);
    Ae4[w * 128 + rp + 1]      = expand16(v.y & 0xFFFFu);
    Ae4[w * 128 + 64 + rp + 1] = expand16(v.y >> 16);
  }
  __syncthreads();

  int lane = t & 63;
  int wv = t >> 6;                   // wave: owns oc32 chunks wv*4 .. wv*4+3
  int g = lane >> 5;
  int col = lane & 31;
  int aoff = (g << 6) + col;         // Ae4 index for (g, row=col)

#pragma unroll 1
  for (int sblk = 0; sblk < 2; sblk++) {
    int oc0 = (wv << 2) + (sblk << 1);
    const unsigned char* bp0 = Bf + ((unsigned)oc0 << 15) + (g << 9) + (col << 4);
    const unsigned char* bp1 = bp0 + 32768;

    v16i acc00 = {0,0,0,0,0,0,0,0,0,0,0,0,0,0,0,0};   // [rt][s]
    v16i acc01 = acc00, acc10 = acc00, acc11 = acc00;

    v4i a0n = Ae4[aoff];
    v4i a1n = Ae4[aoff + 32];
    v4i b0n = *reinterpret_cast<const v4i*>(bp0);
    v4i b1n = *reinterpret_cast<const v4i*>(bp1);
#pragma unroll 1
    for (int ks = 0; ks < 32; ks++) {
      v4i a0 = a0n, a1 = a1n, b0 = b0n, b1 = b1n;
      if (ks < 31) {
        a0n = Ae4[(ks + 1) * 128 + aoff];
        a1n = Ae4[(ks + 1) * 128 + aoff + 32];
        b0n = *reinterpret_cast<const v4i*>(bp0 + (ks + 1) * 1024);
        b1n = *reinterpret_cast<const v4i*>(bp1 + (ks + 1) * 1024);
      }
      acc00 = __builtin_amdgcn_mfma_i32_32x32x32_i8(a0, b0, acc00, 0, 0, 0);
      acc10 = __builtin_amdgcn_mfma_i32_32x32x32_i8(a1, b0, acc10, 0, 0, 0);
      acc01 = __builtin_amdgcn_mfma_i32_32x32x32_i8(a0, b1, acc01, 0, 0, 0);
      acc11 = __builtin_amdgcn_mfma_i32_32x32x32_i8(a1, b1, acc11, 0, 0, 0);
    }

    // threshold + ballot-pack into xbits
#pragma unroll
    for (int s = 0; s < 2; s++) {
      int oc = oc0 + s;
      int cv = carr[(oc << 5) + col];
#pragma unroll
      for (int rt = 0; rt < 2; rt++) {
        v16i av = (s == 0) ? (rt == 0 ? acc00 : acc10)
                           : (rt == 0 ? acc01 : acc11);
#pragma unroll
        for (int reg = 0; reg < 16; reg++) {
          int px_lo = (rt << 5) + (reg & 3) + ((reg >> 2) << 3);
          int px = px_lo + (g << 2);
          bool bit = (2 * av[reg]) > (cv + spopx[px]);
          unsigned long long bal = __ballot(bit);
          if (lane == 0) {
            xbits[px_lo * 32 + oc]       = (unsigned)bal;
            xbits[(px_lo + 4) * 32 + oc] = (unsigned)(bal >> 32);
          }
        }
      }
    }
  }
  __syncthreads();

  // fused layer-2 + epilogue (xbits reads staggered by px to avoid conflicts)
  int px = t >> 3, sub = t & 7;
  if (sub < 3) {
    int c = sub;
    int n = n0 + px;
    int val = 0;
#pragma unroll
    for (int b = 0; b < 8; b++) {
      int o = c * 8 + b;
      unsigned acc2 = 0;
#pragma unroll
      for (int wi = 0; wi < 32; wi++) {
        int w = (wi + px) & 31;
        acc2 += __popc(xbits[px * 32 + w] ^ lm2[o * 32 + w]);
      }
      int bit = ((int)(1024u - acc2)) > thr2[o];
      val |= bit << (7 - b);                            // MSB-first
    }
    out[c * 65536 + n] = (float)val;
    out[196608 + c * 65536 + n] = (float)val - image[c * 65536 + n];
  }
}

extern "C" void kernel_launch(void* const* d_in, const int* in_sizes, int n_in,
                              void* d_out, int out_size, void* d_ws, size_t ws_size,
                              hipStream_t stream) {
  const float*         image = (const float*)d_in[0];
  const unsigned char* mask0 = (const unsigned char*)d_in[1];
  const int*           thr0  = (const int*)d_in[2];
  const unsigned char* mask1 = (const unsigned char*)d_in[3];
  const int*           thr1  = (const int*)d_in[4];
  const unsigned char* mask2 = (const unsigned char*)d_in[5];
  const int*           thr2  = (const int*)d_in[6];
  char* ws = (char*)d_ws;
  unsigned*       X1pT  = (unsigned*)(ws);
  unsigned short* popxA = (unsigned short*)(ws + WS_POPX);
  signed char*    cA    = (signed char*)(ws + WS_CA);
  unsigned char*  cB    = (unsigned char*)(ws + WS_CB);
  unsigned*       M2p   = (unsigned*)(ws + WS_M2P);
  int*            carr  = (int*)(ws + WS_CARR);
  unsigned char*  Bf    = (unsigned char*)(ws + WS_BF);
  float* out = (float*)d_out;

  hipLaunchKernelGGL(prep_kernel, dim3(3075), dim3(256), 0, stream,
                     mask0, thr0, mask1, mask2, cA, cB, Bf, M2p);
  hipLaunchKernelGGL(popm_kernel, dim3(1024), dim3(64), 0, stream,
                     Bf, thr1, carr);
  hipLaunchKernelGGL(pack_x1, dim3(65536), dim3(256), 0, stream,
                     cA, cB, X1pT, popxA);
  hipLaunchKernelGGL(main_kernel, dim3(1024), dim3(512), 0, stream,
                     X1pT, Bf, carr, popxA, M2p, thr2, image, out);
}